// Round 3
// baseline (1979.675 us; speedup 1.0000x reference)
//
#include <hip/hip_runtime.h>
#include <hip/hip_bf16.h>

// ---------------------------------------------------------------------------
// DHN 2-layer hom-conv GNN.
// Round 3: kill CSR fill's 17x write amplification (160MB HBM writes/dispatch).
// Replace hist+scan+fill+csr_agg with:
//   (1) block-aggregated bucket partition of all 6 maps (coalesced writes)
//   (2) per-bucket LDS-atomic aggregation (16KB accum tile, no global atomics)
// ---------------------------------------------------------------------------

#define BM 64
#define BK 16
#define CAP 1280          // bucket capacity: mean 1024, sigma 32 -> +8 sigma
#define CHUNK 32768       // edges per partition block

// out[:, g*64 : g*64+64] = act(in)[M,K] @ Wg[K,64] + bg ; grid (ceil(M/64), 3)
__global__ void gemm_k64(const float* __restrict__ in, int M, int K,
                         const float* __restrict__ W0, const float* __restrict__ W1,
                         const float* __restrict__ W2,
                         const float* __restrict__ b0, const float* __restrict__ b1,
                         const float* __restrict__ b2,
                         float* __restrict__ out) {
    __shared__ float As[BK][BM + 1];
    __shared__ float Ws[BK][64];

    const int g = blockIdx.y;
    const float* W    = (g == 0) ? W0 : ((g == 1) ? W1 : W2);
    const float* bias = (g == 0) ? b0 : ((g == 1) ? b1 : b2);

    const int m0 = blockIdx.x * BM;
    const int t  = threadIdx.x;
    const int tr = t >> 4;
    const int tc = t & 15;

    float acc[4][4] = {};

    for (int k0 = 0; k0 < K; k0 += BK) {
        {
            int m  = t >> 2;
            int kq = (t & 3) * 4;
            int row = m0 + m;
            float4 v = make_float4(0.f, 0.f, 0.f, 0.f);
            if (row < M)
                v = *reinterpret_cast<const float4*>(in + (size_t)row * K + k0 + kq);
            As[kq + 0][m] = v.x; As[kq + 1][m] = v.y;
            As[kq + 2][m] = v.z; As[kq + 3][m] = v.w;
        }
        {
            int k  = t >> 4;
            int nq = (t & 15) * 4;
            float4 w = *reinterpret_cast<const float4*>(W + (size_t)(k0 + k) * 64 + nq);
            *reinterpret_cast<float4*>(&Ws[k][nq]) = w;
        }
        __syncthreads();
        #pragma unroll
        for (int k = 0; k < BK; ++k) {
            float a[4], w[4];
            #pragma unroll
            for (int i = 0; i < 4; ++i) a[i] = As[k][tr * 4 + i];
            #pragma unroll
            for (int j = 0; j < 4; ++j) w[j] = Ws[k][tc * 4 + j];
            #pragma unroll
            for (int i = 0; i < 4; ++i)
                #pragma unroll
                for (int j = 0; j < 4; ++j)
                    acc[i][j] += a[i] * w[j];
        }
        __syncthreads();
    }

    #pragma unroll
    for (int i = 0; i < 4; ++i) {
        int row = m0 + tr * 4 + i;
        if (row < M) {
            #pragma unroll
            for (int j = 0; j < 4; ++j) {
                int col = tc * 4 + j;
                out[(size_t)row * 192 + g * 64 + col] = acc[i][j] + bias[col];
            }
        }
    }
}

// ---- bucket partition: all 6 maps, grid (ceil(E/CHUNK), 6), block 256 ----
// record = src<<6 | (dst&63), written to part[(m*NB+b)*CAP + pos].
// Block-aggregated claiming: one global atomic per (block,bucket), writes per
// bucket are a contiguous ~160B run from one CU -> coalesce in its L2.
__global__ void partition_kernel(const int* __restrict__ m0, const int* __restrict__ m1,
                                 const int* __restrict__ m2, const int* __restrict__ m3,
                                 const int* __restrict__ m4, const int* __restrict__ m5,
                                 int E, int NB, int* __restrict__ cnt,
                                 unsigned* __restrict__ part) {
    const int m = blockIdx.y;
    const int* mp = (m == 0) ? m0 : (m == 1) ? m1 : (m == 2) ? m2
                  : (m == 3) ? m3 : (m == 4) ? m4 : m5;
    __shared__ int hist[800];
    __shared__ int base[800];
    const int c0 = blockIdx.x * CHUNK;
    const int c1 = min(c0 + CHUNK, E);

    for (int i = threadIdx.x; i < NB; i += 256) hist[i] = 0;
    __syncthreads();
    for (int e = c0 + threadIdx.x; e < c1; e += 256)
        atomicAdd(&hist[mp[e] >> 6], 1);
    __syncthreads();
    for (int i = threadIdx.x; i < NB; i += 256) {
        int c = hist[i];
        base[i] = (c > 0) ? atomicAdd(&cnt[m * NB + i], c) : 0;
    }
    __syncthreads();
    for (int i = threadIdx.x; i < NB; i += 256) hist[i] = base[i];
    __syncthreads();
    for (int e = c0 + threadIdx.x; e < c1; e += 256) {
        int dst = mp[e];
        int src = mp[E + e];
        int b = dst >> 6;
        int pos = atomicAdd(&hist[b], 1);
        if (pos < CAP)
            part[(size_t)(m * NB + b) * CAP + pos] = ((unsigned)src << 6) | (unsigned)(dst & 63);
    }
}

// ---- per-bucket aggregation: grid (NB, 3), block 256 (4 waves) ----
// LDS accum[64 dst][64 feat]; ds_add_f32 atomics (lane->bank conflict-free);
// 4 gathers in flight per wave; coalesced relu'd stores.
__global__ void bucket_agg(const float* __restrict__ h, const int* __restrict__ cnt,
                           const unsigned* __restrict__ part, int N, int NB, int mapBase,
                           float* __restrict__ f) {
    const int g = blockIdx.y;
    const int m = mapBase + g;
    const int b = blockIdx.x;
    __shared__ float accum[64][64];
    const int t = threadIdx.x;
    const int lane = t & 63;
    const int wv = t >> 6;

    for (int i = t; i < 4096; i += 256) ((float*)accum)[i] = 0.f;
    __syncthreads();

    const int count = min(cnt[m * NB + b], CAP);
    const unsigned* pr = part + (size_t)(m * NB + b) * CAP;
    const float* hg = h + g * 64 + lane;

    const int q = (count + 3) >> 2;
    const int s = wv * q;
    const int e = min(s + q, count);
    int i = s;
    for (; i + 3 < e; i += 4) {
        unsigned r0 = pr[i], r1 = pr[i + 1], r2 = pr[i + 2], r3 = pr[i + 3];
        float v0 = hg[(size_t)(r0 >> 6) * 192];
        float v1 = hg[(size_t)(r1 >> 6) * 192];
        float v2 = hg[(size_t)(r2 >> 6) * 192];
        float v3 = hg[(size_t)(r3 >> 6) * 192];
        atomicAdd(&accum[r0 & 63][lane], v0);
        atomicAdd(&accum[r1 & 63][lane], v1);
        atomicAdd(&accum[r2 & 63][lane], v2);
        atomicAdd(&accum[r3 & 63][lane], v3);
    }
    for (; i < e; ++i) {
        unsigned r = pr[i];
        atomicAdd(&accum[r & 63][lane], hg[(size_t)(r >> 6) * 192]);
    }
    __syncthreads();

    for (int r = wv; r < 64; r += 4) {
        int n = b * 64 + r;
        if (n < N) f[(size_t)n * 192 + g * 64 + lane] = fmaxf(accum[r][lane], 0.f);
    }
}

// segment-pool f (already relu'd) by sorted batch_idx.
__global__ void pool_kernel(const float* __restrict__ f, const int* __restrict__ bidx,
                            int N, float* __restrict__ pooled) {
    const int c  = threadIdx.x;          // 0..191
    const int r0 = blockIdx.x * 256;
    const int r1 = min(r0 + 256, N);
    if (r0 >= N) return;
    float acc = 0.f;
    int cur = bidx[r0];
    for (int r = r0; r < r1; ++r) {
        int b = bidx[r];
        if (b != cur) {
            atomicAdd(&pooled[(size_t)cur * 192 + c], acc);
            acc = 0.f;
            cur = b;
        }
        acc += f[(size_t)r * 192 + c];
    }
    atomicAdd(&pooled[(size_t)cur * 192 + c], acc);
}

__global__ void mlp_kernel(const float* __restrict__ pooled,
                           const float* __restrict__ A1, const float* __restrict__ ba1,
                           const float* __restrict__ A2, const float* __restrict__ ba2,
                           float* __restrict__ out) {
    __shared__ float p[192];
    __shared__ float hid[256];
    const int b = blockIdx.x;
    const int t = threadIdx.x;
    if (t < 192) p[t] = pooled[(size_t)b * 192 + t];
    __syncthreads();
    float acc = ba1[t];
    for (int k = 0; k < 192; ++k) acc += p[k] * A1[(size_t)k * 256 + t];
    hid[t] = fmaxf(acc, 0.f);
    __syncthreads();
    if (t < 10) {
        float o = ba2[t];
        for (int k = 0; k < 256; ++k) o += hid[k] * A2[(size_t)k * 10 + t];
        out[(size_t)b * 10 + t] = o;
    }
}

extern "C" void kernel_launch(void* const* d_in, const int* in_sizes, int n_in,
                              void* d_out, int out_size, void* d_ws, size_t ws_size,
                              hipStream_t stream) {
    const float* x      = (const float*)d_in[0];
    const int*   map00  = (const int*)d_in[1];
    const int*   map01  = (const int*)d_in[2];
    const int*   map02  = (const int*)d_in[3];
    const int*   map10  = (const int*)d_in[4];
    const int*   map11  = (const int*)d_in[5];
    const int*   map12  = (const int*)d_in[6];
    const int*   bidx   = (const int*)d_in[7];
    const float* W00 = (const float*)d_in[9];  const float* b00 = (const float*)d_in[10];
    const float* W01 = (const float*)d_in[11]; const float* b01 = (const float*)d_in[12];
    const float* W02 = (const float*)d_in[13]; const float* b02 = (const float*)d_in[14];
    const float* W10 = (const float*)d_in[15]; const float* b10 = (const float*)d_in[16];
    const float* W11 = (const float*)d_in[17]; const float* b11 = (const float*)d_in[18];
    const float* W12 = (const float*)d_in[19]; const float* b12 = (const float*)d_in[20];
    const float* A1  = (const float*)d_in[21]; const float* ba1 = (const float*)d_in[22];
    const float* A2  = (const float*)d_in[23]; const float* ba2 = (const float*)d_in[24];

    const int N  = in_sizes[0] / 128;
    const int E  = in_sizes[1] / 2;
    const int NB = (N + 63) >> 6;              // 782 buckets of 64 nodes

    float*    bufH   = (float*)d_ws;                       // [N,192]
    float*    bufF   = bufH + (size_t)N * 192;             // [N,192]
    float*    pooled = bufF + (size_t)N * 192;             // [64,192]
    int*      cnt    = (int*)(pooled + 64 * 192);          // 6*NB
    unsigned* part   = (unsigned*)(cnt + 6 * NB);          // 6*NB*CAP

    dim3 gemmGrid((N + BM - 1) / BM, 3);
    dim3 partGrid((E + CHUNK - 1) / CHUNK, 6);
    dim3 aggGrid(NB, 3);

    // partition all 6 maps up front
    hipMemsetAsync(cnt, 0, (size_t)6 * NB * sizeof(int), stream);
    partition_kernel<<<partGrid, 256, 0, stream>>>(map00, map01, map02,
                                                   map10, map11, map12,
                                                   E, NB, cnt, part);
    // layer 0
    gemm_k64<<<gemmGrid, 256, 0, stream>>>(x, N, 128, W00, W01, W02, b00, b01, b02, bufH);
    bucket_agg<<<aggGrid, 256, 0, stream>>>(bufH, cnt, part, N, NB, 0, bufF);
    // layer 1
    gemm_k64<<<gemmGrid, 256, 0, stream>>>(bufF, N, 192, W10, W11, W12, b10, b11, b12, bufH);
    bucket_agg<<<aggGrid, 256, 0, stream>>>(bufH, cnt, part, N, NB, 3, bufF);
    // pool + mlp
    hipMemsetAsync(pooled, 0, 64 * 192 * sizeof(float), stream);
    pool_kernel<<<(N + 255) / 256, 192, 0, stream>>>(bufF, bidx, N, pooled);
    mlp_kernel<<<64, 256, 0, stream>>>(pooled, A1, ba1, A2, ba2, (float*)d_out);
}

// Round 4
// 518.223 us; speedup vs baseline: 3.8201x; 3.8201x over previous
//
#include <hip/hip_runtime.h>
#include <hip/hip_bf16.h>

// ---------------------------------------------------------------------------
// DHN 2-layer hom-conv GNN.
// Round 4: partition (R3, fast coalesced build) + per-bucket LDS counting sort
// -> CSR, then round-2-style wave-per-node csr_agg (high MLP won round 2).
// Removes fill_kernel (2x200us write-amp) and bucket_agg (855us latency-bound).
// ---------------------------------------------------------------------------

#define BM 64
#define BK 16
#define CAP 1280          // bucket capacity: mean 1024, sigma 32 -> +8 sigma
#define CHUNK 32768       // edges per partition block

// out[:, g*64 : g*64+64] = in[M,K] @ Wg[K,64] + bg ; grid (ceil(M/64), 3)
__global__ void gemm_k64(const float* __restrict__ in, int M, int K,
                         const float* __restrict__ W0, const float* __restrict__ W1,
                         const float* __restrict__ W2,
                         const float* __restrict__ b0, const float* __restrict__ b1,
                         const float* __restrict__ b2,
                         float* __restrict__ out) {
    __shared__ float As[BK][BM + 1];
    __shared__ float Ws[BK][64];

    const int g = blockIdx.y;
    const float* W    = (g == 0) ? W0 : ((g == 1) ? W1 : W2);
    const float* bias = (g == 0) ? b0 : ((g == 1) ? b1 : b2);

    const int m0 = blockIdx.x * BM;
    const int t  = threadIdx.x;
    const int tr = t >> 4;
    const int tc = t & 15;

    float acc[4][4] = {};

    for (int k0 = 0; k0 < K; k0 += BK) {
        {
            int m  = t >> 2;
            int kq = (t & 3) * 4;
            int row = m0 + m;
            float4 v = make_float4(0.f, 0.f, 0.f, 0.f);
            if (row < M)
                v = *reinterpret_cast<const float4*>(in + (size_t)row * K + k0 + kq);
            As[kq + 0][m] = v.x; As[kq + 1][m] = v.y;
            As[kq + 2][m] = v.z; As[kq + 3][m] = v.w;
        }
        {
            int k  = t >> 4;
            int nq = (t & 15) * 4;
            float4 w = *reinterpret_cast<const float4*>(W + (size_t)(k0 + k) * 64 + nq);
            *reinterpret_cast<float4*>(&Ws[k][nq]) = w;
        }
        __syncthreads();
        #pragma unroll
        for (int k = 0; k < BK; ++k) {
            float a[4], w[4];
            #pragma unroll
            for (int i = 0; i < 4; ++i) a[i] = As[k][tr * 4 + i];
            #pragma unroll
            for (int j = 0; j < 4; ++j) w[j] = Ws[k][tc * 4 + j];
            #pragma unroll
            for (int i = 0; i < 4; ++i)
                #pragma unroll
                for (int j = 0; j < 4; ++j)
                    acc[i][j] += a[i] * w[j];
        }
        __syncthreads();
    }

    #pragma unroll
    for (int i = 0; i < 4; ++i) {
        int row = m0 + tr * 4 + i;
        if (row < M) {
            #pragma unroll
            for (int j = 0; j < 4; ++j) {
                int col = tc * 4 + j;
                out[(size_t)row * 192 + g * 64 + col] = acc[i][j] + bias[col];
            }
        }
    }
}

// ---- bucket partition: all 6 maps, grid (ceil(E/CHUNK), 6), block 256 ----
// record = src<<6 | (dst&63), written to part[(m*NB+b)*CAP + pos].
__global__ void partition_kernel(const int* __restrict__ m0, const int* __restrict__ m1,
                                 const int* __restrict__ m2, const int* __restrict__ m3,
                                 const int* __restrict__ m4, const int* __restrict__ m5,
                                 int E, int NB, int* __restrict__ cnt,
                                 unsigned* __restrict__ part) {
    const int m = blockIdx.y;
    const int* mp = (m == 0) ? m0 : (m == 1) ? m1 : (m == 2) ? m2
                  : (m == 3) ? m3 : (m == 4) ? m4 : m5;
    __shared__ int hist[800];
    __shared__ int base[800];
    const int c0 = blockIdx.x * CHUNK;
    const int c1 = min(c0 + CHUNK, E);

    for (int i = threadIdx.x; i < NB; i += 256) hist[i] = 0;
    __syncthreads();
    for (int e = c0 + threadIdx.x; e < c1; e += 256)
        atomicAdd(&hist[mp[e] >> 6], 1);
    __syncthreads();
    for (int i = threadIdx.x; i < NB; i += 256) {
        int c = hist[i];
        base[i] = (c > 0) ? atomicAdd(&cnt[m * NB + i], c) : 0;
    }
    __syncthreads();
    for (int i = threadIdx.x; i < NB; i += 256) hist[i] = base[i];
    __syncthreads();
    for (int e = c0 + threadIdx.x; e < c1; e += 256) {
        int dst = mp[e];
        int src = mp[E + e];
        int b = dst >> 6;
        int pos = atomicAdd(&hist[b], 1);
        if (pos < CAP)
            part[(size_t)(m * NB + b) * CAP + pos] = ((unsigned)src << 6) | (unsigned)(dst & 63);
    }
}

// ---- per-bucket LDS counting sort -> CSR. grid (NB, 6), block 256 ----
// In-place within the bucket's CAP slots: part[base+i] becomes plain src,
// grouped by local dst. rows[m*N+n] = global END offset of node n's run.
__global__ void bucket_sort(int NB, int N, const int* __restrict__ cnt,
                            unsigned* __restrict__ part, int* __restrict__ rows) {
    const int b = blockIdx.x;
    const int m = blockIdx.y;
    __shared__ unsigned rec[CAP];
    __shared__ int cOff[64];
    __shared__ int pl[64];
    const int base = (m * NB + b) * CAP;
    const int c = min(cnt[m * NB + b], CAP);

    for (int i = threadIdx.x; i < c; i += 256) rec[i] = part[base + i];
    if (threadIdx.x < 64) cOff[threadIdx.x] = 0;
    __syncthreads();
    for (int i = threadIdx.x; i < c; i += 256) atomicAdd(&cOff[rec[i] & 63], 1);
    __syncthreads();
    if (threadIdx.x == 0) {
        int run = 0;
        for (int r = 0; r < 64; ++r) { int t = cOff[r]; cOff[r] = run; run += t; }
    }
    __syncthreads();
    if (threadIdx.x < 64) {
        pl[threadIdx.x] = cOff[threadIdx.x];
        int n = b * 64 + threadIdx.x;
        if (n < N)
            rows[(size_t)m * N + n] = base + ((threadIdx.x == 63) ? c : cOff[threadIdx.x + 1]);
    }
    __syncthreads();
    for (int i = threadIdx.x; i < c; i += 256) {
        unsigned r = rec[i];
        int pos = atomicAdd(&pl[r & 63], 1);
        part[base + pos] = r >> 6;
    }
}

// ---- wave per (node, map); lane = feature. relu fused into store. ----
// grid ((N+3)/4, 3), block 256. High wave count = high gather MLP (round-2 win).
__global__ void csr_agg(const float* __restrict__ h, const int* __restrict__ rows,
                        const unsigned* __restrict__ cols, int N, int NB, int mapBase,
                        float* __restrict__ f) {
    const int g = blockIdx.y;
    const int m = mapBase + g;
    const int lane = threadIdx.x & 63;
    int n = (blockIdx.x * blockDim.x + threadIdx.x) >> 6;
    if (n >= N) return;
    const int base = (m * NB + (n >> 6)) * CAP;
    int s = ((n & 63) == 0) ? base : rows[(size_t)m * N + n - 1];
    int e = rows[(size_t)m * N + n];
    const float* hg = h + g * 64 + lane;
    float acc = 0.f;
    int i = s;
    for (; i + 3 < e; i += 4) {
        unsigned s0 = cols[i], s1 = cols[i + 1], s2 = cols[i + 2], s3 = cols[i + 3];
        float v0 = hg[(size_t)s0 * 192];
        float v1 = hg[(size_t)s1 * 192];
        float v2 = hg[(size_t)s2 * 192];
        float v3 = hg[(size_t)s3 * 192];
        acc += (v0 + v1) + (v2 + v3);
    }
    for (; i < e; ++i) acc += hg[(size_t)cols[i] * 192];
    f[(size_t)n * 192 + g * 64 + lane] = fmaxf(acc, 0.f);
}

// segment-pool f (already relu'd) by sorted batch_idx.
__global__ void pool_kernel(const float* __restrict__ f, const int* __restrict__ bidx,
                            int N, float* __restrict__ pooled) {
    const int c  = threadIdx.x;          // 0..191
    const int r0 = blockIdx.x * 256;
    const int r1 = min(r0 + 256, N);
    if (r0 >= N) return;
    float acc = 0.f;
    int cur = bidx[r0];
    for (int r = r0; r < r1; ++r) {
        int b = bidx[r];
        if (b != cur) {
            atomicAdd(&pooled[(size_t)cur * 192 + c], acc);
            acc = 0.f;
            cur = b;
        }
        acc += f[(size_t)r * 192 + c];
    }
    atomicAdd(&pooled[(size_t)cur * 192 + c], acc);
}

__global__ void mlp_kernel(const float* __restrict__ pooled,
                           const float* __restrict__ A1, const float* __restrict__ ba1,
                           const float* __restrict__ A2, const float* __restrict__ ba2,
                           float* __restrict__ out) {
    __shared__ float p[192];
    __shared__ float hid[256];
    const int b = blockIdx.x;
    const int t = threadIdx.x;
    if (t < 192) p[t] = pooled[(size_t)b * 192 + t];
    __syncthreads();
    float acc = ba1[t];
    for (int k = 0; k < 192; ++k) acc += p[k] * A1[(size_t)k * 256 + t];
    hid[t] = fmaxf(acc, 0.f);
    __syncthreads();
    if (t < 10) {
        float o = ba2[t];
        for (int k = 0; k < 256; ++k) o += hid[k] * A2[(size_t)k * 10 + t];
        out[(size_t)b * 10 + t] = o;
    }
}

extern "C" void kernel_launch(void* const* d_in, const int* in_sizes, int n_in,
                              void* d_out, int out_size, void* d_ws, size_t ws_size,
                              hipStream_t stream) {
    const float* x      = (const float*)d_in[0];
    const int*   map00  = (const int*)d_in[1];
    const int*   map01  = (const int*)d_in[2];
    const int*   map02  = (const int*)d_in[3];
    const int*   map10  = (const int*)d_in[4];
    const int*   map11  = (const int*)d_in[5];
    const int*   map12  = (const int*)d_in[6];
    const int*   bidx   = (const int*)d_in[7];
    const float* W00 = (const float*)d_in[9];  const float* b00 = (const float*)d_in[10];
    const float* W01 = (const float*)d_in[11]; const float* b01 = (const float*)d_in[12];
    const float* W02 = (const float*)d_in[13]; const float* b02 = (const float*)d_in[14];
    const float* W10 = (const float*)d_in[15]; const float* b10 = (const float*)d_in[16];
    const float* W11 = (const float*)d_in[17]; const float* b11 = (const float*)d_in[18];
    const float* W12 = (const float*)d_in[19]; const float* b12 = (const float*)d_in[20];
    const float* A1  = (const float*)d_in[21]; const float* ba1 = (const float*)d_in[22];
    const float* A2  = (const float*)d_in[23]; const float* ba2 = (const float*)d_in[24];

    const int N  = in_sizes[0] / 128;
    const int E  = in_sizes[1] / 2;
    const int NB = (N + 63) >> 6;              // 782 buckets of 64 nodes

    float*    bufH   = (float*)d_ws;                       // [N,192]
    float*    bufF   = bufH + (size_t)N * 192;             // [N,192]
    float*    pooled = bufF + (size_t)N * 192;             // [64,192]
    int*      cnt    = (int*)(pooled + 64 * 192);          // 6*NB
    unsigned* part   = (unsigned*)(cnt + 6 * NB);          // 6*NB*CAP
    int*      rows   = (int*)(part + (size_t)6 * NB * CAP);// 6*N

    dim3 gemmGrid((N + BM - 1) / BM, 3);
    dim3 partGrid((E + CHUNK - 1) / CHUNK, 6);
    dim3 sortGrid(NB, 6);
    dim3 aggGrid((N + 3) / 4, 3);

    // build CSR for all 6 maps up front
    hipMemsetAsync(cnt, 0, (size_t)6 * NB * sizeof(int), stream);
    partition_kernel<<<partGrid, 256, 0, stream>>>(map00, map01, map02,
                                                   map10, map11, map12,
                                                   E, NB, cnt, part);
    bucket_sort<<<sortGrid, 256, 0, stream>>>(NB, N, cnt, part, rows);
    // layer 0
    gemm_k64<<<gemmGrid, 256, 0, stream>>>(x, N, 128, W00, W01, W02, b00, b01, b02, bufH);
    csr_agg<<<aggGrid, 256, 0, stream>>>(bufH, rows, part, N, NB, 0, bufF);
    // layer 1
    gemm_k64<<<gemmGrid, 256, 0, stream>>>(bufF, N, 192, W10, W11, W12, b10, b11, b12, bufH);
    csr_agg<<<aggGrid, 256, 0, stream>>>(bufH, rows, part, N, NB, 3, bufF);
    // pool + mlp
    hipMemsetAsync(pooled, 0, 64 * 192 * sizeof(float), stream);
    pool_kernel<<<(N + 255) / 256, 192, 0, stream>>>(bufF, bidx, N, pooled);
    mlp_kernel<<<64, 256, 0, stream>>>(pooled, A1, ba1, A2, ba2, (float*)d_out);
}

// Round 5
// 461.820 us; speedup vs baseline: 4.2867x; 1.1221x over previous
//
#include <hip/hip_runtime.h>
#include <hip/hip_bf16.h>

// ---------------------------------------------------------------------------
// DHN 2-layer hom-conv GNN.
// Round 5: partition_kernel was parallelism-starved (150 blocks, 6.3% occ,
// 165us). CHUNK 32768->16384, block 256->512: 300 blocks x 8 waves covers all
// 256 CUs. Write-run length halves (41->20 recs) -- ~+15% write amp, cheap.
// ---------------------------------------------------------------------------

#define BM 64
#define BK 16
#define CAP 1280          // bucket capacity: mean 1024, sigma 32 -> +8 sigma
#define CHUNK 16384       // edges per partition block
#define PTHREADS 512

// out[:, g*64 : g*64+64] = in[M,K] @ Wg[K,64] + bg ; grid (ceil(M/64), 3)
__global__ void gemm_k64(const float* __restrict__ in, int M, int K,
                         const float* __restrict__ W0, const float* __restrict__ W1,
                         const float* __restrict__ W2,
                         const float* __restrict__ b0, const float* __restrict__ b1,
                         const float* __restrict__ b2,
                         float* __restrict__ out) {
    __shared__ float As[BK][BM + 1];
    __shared__ float Ws[BK][64];

    const int g = blockIdx.y;
    const float* W    = (g == 0) ? W0 : ((g == 1) ? W1 : W2);
    const float* bias = (g == 0) ? b0 : ((g == 1) ? b1 : b2);

    const int m0 = blockIdx.x * BM;
    const int t  = threadIdx.x;
    const int tr = t >> 4;
    const int tc = t & 15;

    float acc[4][4] = {};

    for (int k0 = 0; k0 < K; k0 += BK) {
        {
            int m  = t >> 2;
            int kq = (t & 3) * 4;
            int row = m0 + m;
            float4 v = make_float4(0.f, 0.f, 0.f, 0.f);
            if (row < M)
                v = *reinterpret_cast<const float4*>(in + (size_t)row * K + k0 + kq);
            As[kq + 0][m] = v.x; As[kq + 1][m] = v.y;
            As[kq + 2][m] = v.z; As[kq + 3][m] = v.w;
        }
        {
            int k  = t >> 4;
            int nq = (t & 15) * 4;
            float4 w = *reinterpret_cast<const float4*>(W + (size_t)(k0 + k) * 64 + nq);
            *reinterpret_cast<float4*>(&Ws[k][nq]) = w;
        }
        __syncthreads();
        #pragma unroll
        for (int k = 0; k < BK; ++k) {
            float a[4], w[4];
            #pragma unroll
            for (int i = 0; i < 4; ++i) a[i] = As[k][tr * 4 + i];
            #pragma unroll
            for (int j = 0; j < 4; ++j) w[j] = Ws[k][tc * 4 + j];
            #pragma unroll
            for (int i = 0; i < 4; ++i)
                #pragma unroll
                for (int j = 0; j < 4; ++j)
                    acc[i][j] += a[i] * w[j];
        }
        __syncthreads();
    }

    #pragma unroll
    for (int i = 0; i < 4; ++i) {
        int row = m0 + tr * 4 + i;
        if (row < M) {
            #pragma unroll
            for (int j = 0; j < 4; ++j) {
                int col = tc * 4 + j;
                out[(size_t)row * 192 + g * 64 + col] = acc[i][j] + bias[col];
            }
        }
    }
}

// ---- bucket partition: all 6 maps, grid (ceil(E/CHUNK), 6), block 512 ----
// record = src<<6 | (dst&63), written to part[(m*NB+b)*CAP + pos].
__global__ void partition_kernel(const int* __restrict__ m0, const int* __restrict__ m1,
                                 const int* __restrict__ m2, const int* __restrict__ m3,
                                 const int* __restrict__ m4, const int* __restrict__ m5,
                                 int E, int NB, int* __restrict__ cnt,
                                 unsigned* __restrict__ part) {
    const int m = blockIdx.y;
    const int* mp = (m == 0) ? m0 : (m == 1) ? m1 : (m == 2) ? m2
                  : (m == 3) ? m3 : (m == 4) ? m4 : m5;
    __shared__ int hist[800];
    __shared__ int base[800];
    const int c0 = blockIdx.x * CHUNK;
    const int c1 = min(c0 + CHUNK, E);

    for (int i = threadIdx.x; i < NB; i += PTHREADS) hist[i] = 0;
    __syncthreads();
    for (int e = c0 + threadIdx.x; e < c1; e += PTHREADS)
        atomicAdd(&hist[mp[e] >> 6], 1);
    __syncthreads();
    for (int i = threadIdx.x; i < NB; i += PTHREADS) {
        int c = hist[i];
        base[i] = (c > 0) ? atomicAdd(&cnt[m * NB + i], c) : 0;
    }
    __syncthreads();
    for (int i = threadIdx.x; i < NB; i += PTHREADS) hist[i] = base[i];
    __syncthreads();
    for (int e = c0 + threadIdx.x; e < c1; e += PTHREADS) {
        int dst = mp[e];
        int src = mp[E + e];
        int b = dst >> 6;
        int pos = atomicAdd(&hist[b], 1);
        if (pos < CAP)
            part[(size_t)(m * NB + b) * CAP + pos] = ((unsigned)src << 6) | (unsigned)(dst & 63);
    }
}

// ---- per-bucket LDS counting sort -> CSR. grid (NB, 6), block 256 ----
// In-place within the bucket's CAP slots: part[base+i] becomes plain src,
// grouped by local dst. rows[m*N+n] = global END offset of node n's run.
__global__ void bucket_sort(int NB, int N, const int* __restrict__ cnt,
                            unsigned* __restrict__ part, int* __restrict__ rows) {
    const int b = blockIdx.x;
    const int m = blockIdx.y;
    __shared__ unsigned rec[CAP];
    __shared__ int cOff[64];
    __shared__ int pl[64];
    const int base = (m * NB + b) * CAP;
    const int c = min(cnt[m * NB + b], CAP);

    for (int i = threadIdx.x; i < c; i += 256) rec[i] = part[base + i];
    if (threadIdx.x < 64) cOff[threadIdx.x] = 0;
    __syncthreads();
    for (int i = threadIdx.x; i < c; i += 256) atomicAdd(&cOff[rec[i] & 63], 1);
    __syncthreads();
    if (threadIdx.x == 0) {
        int run = 0;
        for (int r = 0; r < 64; ++r) { int t = cOff[r]; cOff[r] = run; run += t; }
    }
    __syncthreads();
    if (threadIdx.x < 64) {
        pl[threadIdx.x] = cOff[threadIdx.x];
        int n = b * 64 + threadIdx.x;
        if (n < N)
            rows[(size_t)m * N + n] = base + ((threadIdx.x == 63) ? c : cOff[threadIdx.x + 1]);
    }
    __syncthreads();
    for (int i = threadIdx.x; i < c; i += 256) {
        unsigned r = rec[i];
        int pos = atomicAdd(&pl[r & 63], 1);
        part[base + pos] = r >> 6;
    }
}

// ---- wave per (node, map); lane = feature. relu fused into store. ----
__global__ void csr_agg(const float* __restrict__ h, const int* __restrict__ rows,
                        const unsigned* __restrict__ cols, int N, int NB, int mapBase,
                        float* __restrict__ f) {
    const int g = blockIdx.y;
    const int m = mapBase + g;
    const int lane = threadIdx.x & 63;
    int n = (blockIdx.x * blockDim.x + threadIdx.x) >> 6;
    if (n >= N) return;
    const int base = (m * NB + (n >> 6)) * CAP;
    int s = ((n & 63) == 0) ? base : rows[(size_t)m * N + n - 1];
    int e = rows[(size_t)m * N + n];
    const float* hg = h + g * 64 + lane;
    float acc = 0.f;
    int i = s;
    for (; i + 3 < e; i += 4) {
        unsigned s0 = cols[i], s1 = cols[i + 1], s2 = cols[i + 2], s3 = cols[i + 3];
        float v0 = hg[(size_t)s0 * 192];
        float v1 = hg[(size_t)s1 * 192];
        float v2 = hg[(size_t)s2 * 192];
        float v3 = hg[(size_t)s3 * 192];
        acc += (v0 + v1) + (v2 + v3);
    }
    for (; i < e; ++i) acc += hg[(size_t)cols[i] * 192];
    f[(size_t)n * 192 + g * 64 + lane] = fmaxf(acc, 0.f);
}

// segment-pool f (already relu'd) by sorted batch_idx.
__global__ void pool_kernel(const float* __restrict__ f, const int* __restrict__ bidx,
                            int N, float* __restrict__ pooled) {
    const int c  = threadIdx.x;          // 0..191
    const int r0 = blockIdx.x * 256;
    const int r1 = min(r0 + 256, N);
    if (r0 >= N) return;
    float acc = 0.f;
    int cur = bidx[r0];
    for (int r = r0; r < r1; ++r) {
        int b = bidx[r];
        if (b != cur) {
            atomicAdd(&pooled[(size_t)cur * 192 + c], acc);
            acc = 0.f;
            cur = b;
        }
        acc += f[(size_t)r * 192 + c];
    }
    atomicAdd(&pooled[(size_t)cur * 192 + c], acc);
}

__global__ void mlp_kernel(const float* __restrict__ pooled,
                           const float* __restrict__ A1, const float* __restrict__ ba1,
                           const float* __restrict__ A2, const float* __restrict__ ba2,
                           float* __restrict__ out) {
    __shared__ float p[192];
    __shared__ float hid[256];
    const int b = blockIdx.x;
    const int t = threadIdx.x;
    if (t < 192) p[t] = pooled[(size_t)b * 192 + t];
    __syncthreads();
    float acc = ba1[t];
    for (int k = 0; k < 192; ++k) acc += p[k] * A1[(size_t)k * 256 + t];
    hid[t] = fmaxf(acc, 0.f);
    __syncthreads();
    if (t < 10) {
        float o = ba2[t];
        for (int k = 0; k < 256; ++k) o += hid[k] * A2[(size_t)k * 10 + t];
        out[(size_t)b * 10 + t] = o;
    }
}

extern "C" void kernel_launch(void* const* d_in, const int* in_sizes, int n_in,
                              void* d_out, int out_size, void* d_ws, size_t ws_size,
                              hipStream_t stream) {
    const float* x      = (const float*)d_in[0];
    const int*   map00  = (const int*)d_in[1];
    const int*   map01  = (const int*)d_in[2];
    const int*   map02  = (const int*)d_in[3];
    const int*   map10  = (const int*)d_in[4];
    const int*   map11  = (const int*)d_in[5];
    const int*   map12  = (const int*)d_in[6];
    const int*   bidx   = (const int*)d_in[7];
    const float* W00 = (const float*)d_in[9];  const float* b00 = (const float*)d_in[10];
    const float* W01 = (const float*)d_in[11]; const float* b01 = (const float*)d_in[12];
    const float* W02 = (const float*)d_in[13]; const float* b02 = (const float*)d_in[14];
    const float* W10 = (const float*)d_in[15]; const float* b10 = (const float*)d_in[16];
    const float* W11 = (const float*)d_in[17]; const float* b11 = (const float*)d_in[18];
    const float* W12 = (const float*)d_in[19]; const float* b12 = (const float*)d_in[20];
    const float* A1  = (const float*)d_in[21]; const float* ba1 = (const float*)d_in[22];
    const float* A2  = (const float*)d_in[23]; const float* ba2 = (const float*)d_in[24];

    const int N  = in_sizes[0] / 128;
    const int E  = in_sizes[1] / 2;
    const int NB = (N + 63) >> 6;              // 782 buckets of 64 nodes

    float*    bufH   = (float*)d_ws;                       // [N,192]
    float*    bufF   = bufH + (size_t)N * 192;             // [N,192]
    float*    pooled = bufF + (size_t)N * 192;             // [64,192]
    int*      cnt    = (int*)(pooled + 64 * 192);          // 6*NB
    unsigned* part   = (unsigned*)(cnt + 6 * NB);          // 6*NB*CAP
    int*      rows   = (int*)(part + (size_t)6 * NB * CAP);// 6*N

    dim3 gemmGrid((N + BM - 1) / BM, 3);
    dim3 partGrid((E + CHUNK - 1) / CHUNK, 6);
    dim3 sortGrid(NB, 6);
    dim3 aggGrid((N + 3) / 4, 3);

    // build CSR for all 6 maps up front
    hipMemsetAsync(cnt, 0, (size_t)6 * NB * sizeof(int), stream);
    partition_kernel<<<partGrid, PTHREADS, 0, stream>>>(map00, map01, map02,
                                                        map10, map11, map12,
                                                        E, NB, cnt, part);
    bucket_sort<<<sortGrid, 256, 0, stream>>>(NB, N, cnt, part, rows);
    // layer 0
    gemm_k64<<<gemmGrid, 256, 0, stream>>>(x, N, 128, W00, W01, W02, b00, b01, b02, bufH);
    csr_agg<<<aggGrid, 256, 0, stream>>>(bufH, rows, part, N, NB, 0, bufF);
    // layer 1
    gemm_k64<<<gemmGrid, 256, 0, stream>>>(bufF, N, 192, W10, W11, W12, b10, b11, b12, bufH);
    csr_agg<<<aggGrid, 256, 0, stream>>>(bufH, rows, part, N, NB, 3, bufF);
    // pool + mlp
    hipMemsetAsync(pooled, 0, 64 * 192 * sizeof(float), stream);
    pool_kernel<<<(N + 255) / 256, 192, 0, stream>>>(bufF, bidx, N, pooled);
    mlp_kernel<<<64, 256, 0, stream>>>(pooled, A1, ba1, A2, ba2, (float*)d_out);
}

// Round 6
// 408.471 us; speedup vs baseline: 4.8466x; 1.1306x over previous
//
#include <hip/hip_runtime.h>
#include <hip/hip_bf16.h>

// ---------------------------------------------------------------------------
// DHN 2-layer hom-conv GNN.
// Round 6: bf16 data plane. GEMMs -> mfma_f32_16x16x32_bf16 (no fp32 MFMA on
// CDNA4); h stored bf16 so csr_agg gathers 128B/edge instead of 256B.
// W pre-packed to per-fragment [K/8][64][8] bf16; A-tile LDS XOR-swizzled
// (2-way bank aliasing = free). f stays fp32 (gemm converts on load).
// ---------------------------------------------------------------------------

#define CAP 1280          // bucket capacity: mean 1024, sigma 32 -> +8 sigma
#define CHUNK 16384       // edges per partition block
#define PTHREADS 512

typedef __attribute__((ext_vector_type(8))) short bf16x8;
typedef __attribute__((ext_vector_type(4))) float f32x4;

__device__ inline unsigned short f2bf(float x) {           // RNE f32 -> bf16
    union { float f; unsigned u; } c; c.f = x;
    unsigned r = (c.u + 0x7FFFu + ((c.u >> 16) & 1u)) >> 16;
    return (unsigned short)r;
}
__device__ inline float bf2f(unsigned short u) {
    union { unsigned u; float f; } c; c.u = ((unsigned)u) << 16; return c.f;
}

// ---- pack 6 weight matrices [K][64] f32 -> [K/8][64][8] bf16 frags ----
__global__ void prepack_w(const float* __restrict__ W0, const float* __restrict__ W1,
                          const float* __restrict__ W2, const float* __restrict__ W3,
                          const float* __restrict__ W4, const float* __restrict__ W5,
                          unsigned short* __restrict__ wp) {
    const int m = blockIdx.x;
    const float* W = (m == 0) ? W0 : (m == 1) ? W1 : (m == 2) ? W2
                   : (m == 3) ? W3 : (m == 4) ? W4 : W5;
    const int K = (m < 3) ? 128 : 192;
    unsigned short* o = wp + (size_t)m * 12288;
    for (int idx = threadIdx.x; idx < K * 64; idx += 256) {
        int k = idx >> 6, col = idx & 63;
        o[((k >> 3) * 64 + col) * 8 + (k & 7)] = f2bf(W[idx]);
    }
}

// ---- bf16 MFMA gemm: h[:, g*64..] = in[M,K]@Wg + bg, h bf16. ----
// grid (ceil(M/64), 3), block 256 (4 waves, 16 rows each).
__global__ void gemm_mfma(const float* __restrict__ in, int M, int K,
                          const unsigned short* __restrict__ wpack,
                          const float* __restrict__ b0, const float* __restrict__ b1,
                          const float* __restrict__ b2, int mslot,
                          unsigned short* __restrict__ h) {
    __shared__ __align__(16) unsigned short Ws[12288];  // K*64 bf16, K<=192
    __shared__ __align__(16) unsigned short As[2048];   // 64 rows x 32 k, swizzled

    const int g = blockIdx.y;
    const float* bias = (g == 0) ? b0 : ((g == 1) ? b1 : b2);
    const unsigned short* wp = wpack + (size_t)(mslot + g) * 12288;

    const int t = threadIdx.x;
    for (int i = t; i < K * 32; i += 256)            // stage packed W as dwords
        ((int*)Ws)[i] = ((const int*)wp)[i];

    const int m0   = blockIdx.x * 64;
    const int lane = t & 63;
    const int wrow = (t >> 6) * 16;

    // A staging: thread t loads 8 floats of row (t>>2), k-seg (t&3)
    const int arow = t >> 2;
    const int aseg = t & 3;
    const int aswz = arow * 32 + ((aseg ^ ((arow >> 1) & 3)) << 3);
    const int grow = m0 + arow;
    const float* ain = in + (size_t)grow * K + aseg * 8;

    // A fragment read: lane l -> row wrow+(l&15), k-half (l>>4)
    const int lrow = wrow + (lane & 15);
    const int aoff = lrow * 32 + ((((lane >> 4)) ^ ((lrow >> 1) & 3)) << 3);
    const int kq   = lane >> 4;

    f32x4 acc[4] = {};

    const int nsteps = K >> 5;
    for (int s = 0; s < nsteps; ++s) {
        __syncthreads();
        bf16x8 av = {};
        if (grow < M) {
            float4 v0 = *reinterpret_cast<const float4*>(ain + s * 32);
            float4 v1 = *reinterpret_cast<const float4*>(ain + s * 32 + 4);
            av[0] = (short)f2bf(v0.x); av[1] = (short)f2bf(v0.y);
            av[2] = (short)f2bf(v0.z); av[3] = (short)f2bf(v0.w);
            av[4] = (short)f2bf(v1.x); av[5] = (short)f2bf(v1.y);
            av[6] = (short)f2bf(v1.z); av[7] = (short)f2bf(v1.w);
        }
        *reinterpret_cast<bf16x8*>(&As[aswz]) = av;
        __syncthreads();

        bf16x8 af = *reinterpret_cast<const bf16x8*>(&As[aoff]);
        const int kg = s * 4 + kq;
        #pragma unroll
        for (int n = 0; n < 4; ++n) {
            bf16x8 bf = *reinterpret_cast<const bf16x8*>(
                &Ws[(size_t)(kg * 64 + n * 16 + (lane & 15)) * 8]);
            acc[n] = __builtin_amdgcn_mfma_f32_16x16x32_bf16(af, bf, acc[n], 0, 0, 0);
        }
    }

    #pragma unroll
    for (int n = 0; n < 4; ++n) {
        int col = n * 16 + (lane & 15);
        float bv = bias[col];
        #pragma unroll
        for (int r = 0; r < 4; ++r) {
            int row = m0 + wrow + (lane >> 4) * 4 + r;
            if (row < M)
                h[(size_t)row * 192 + g * 64 + col] = f2bf(acc[n][r] + bv);
        }
    }
}

// ---- bucket partition: all 6 maps, grid (ceil(E/CHUNK), 6), block 512 ----
__global__ void partition_kernel(const int* __restrict__ m0, const int* __restrict__ m1,
                                 const int* __restrict__ m2, const int* __restrict__ m3,
                                 const int* __restrict__ m4, const int* __restrict__ m5,
                                 int E, int NB, int* __restrict__ cnt,
                                 unsigned* __restrict__ part) {
    const int m = blockIdx.y;
    const int* mp = (m == 0) ? m0 : (m == 1) ? m1 : (m == 2) ? m2
                  : (m == 3) ? m3 : (m == 4) ? m4 : m5;
    __shared__ int hist[800];
    __shared__ int base[800];
    const int c0 = blockIdx.x * CHUNK;
    const int c1 = min(c0 + CHUNK, E);

    for (int i = threadIdx.x; i < NB; i += PTHREADS) hist[i] = 0;
    __syncthreads();
    for (int e = c0 + threadIdx.x; e < c1; e += PTHREADS)
        atomicAdd(&hist[mp[e] >> 6], 1);
    __syncthreads();
    for (int i = threadIdx.x; i < NB; i += PTHREADS) {
        int c = hist[i];
        base[i] = (c > 0) ? atomicAdd(&cnt[m * NB + i], c) : 0;
    }
    __syncthreads();
    for (int i = threadIdx.x; i < NB; i += PTHREADS) hist[i] = base[i];
    __syncthreads();
    for (int e = c0 + threadIdx.x; e < c1; e += PTHREADS) {
        int dst = mp[e];
        int src = mp[E + e];
        int b = dst >> 6;
        int pos = atomicAdd(&hist[b], 1);
        if (pos < CAP)
            part[(size_t)(m * NB + b) * CAP + pos] = ((unsigned)src << 6) | (unsigned)(dst & 63);
    }
}

// ---- per-bucket LDS counting sort -> CSR. grid (NB, 6), block 256 ----
__global__ void bucket_sort(int NB, int N, const int* __restrict__ cnt,
                            unsigned* __restrict__ part, int* __restrict__ rows) {
    const int b = blockIdx.x;
    const int m = blockIdx.y;
    __shared__ unsigned rec[CAP];
    __shared__ int cOff[64];
    __shared__ int pl[64];
    const int base = (m * NB + b) * CAP;
    const int c = min(cnt[m * NB + b], CAP);

    for (int i = threadIdx.x; i < c; i += 256) rec[i] = part[base + i];
    if (threadIdx.x < 64) cOff[threadIdx.x] = 0;
    __syncthreads();
    for (int i = threadIdx.x; i < c; i += 256) atomicAdd(&cOff[rec[i] & 63], 1);
    __syncthreads();
    if (threadIdx.x == 0) {
        int run = 0;
        for (int r = 0; r < 64; ++r) { int t = cOff[r]; cOff[r] = run; run += t; }
    }
    __syncthreads();
    if (threadIdx.x < 64) {
        pl[threadIdx.x] = cOff[threadIdx.x];
        int n = b * 64 + threadIdx.x;
        if (n < N)
            rows[(size_t)m * N + n] = base + ((threadIdx.x == 63) ? c : cOff[threadIdx.x + 1]);
    }
    __syncthreads();
    for (int i = threadIdx.x; i < c; i += 256) {
        unsigned r = rec[i];
        int pos = atomicAdd(&pl[r & 63], 1);
        part[base + pos] = r >> 6;
    }
}

// ---- wave per (node, map); lane = feature; bf16 gather, fp32 accum ----
__global__ void csr_agg(const unsigned short* __restrict__ h, const int* __restrict__ rows,
                        const unsigned* __restrict__ cols, int N, int NB, int mapBase,
                        float* __restrict__ f) {
    const int g = blockIdx.y;
    const int m = mapBase + g;
    const int lane = threadIdx.x & 63;
    int n = (blockIdx.x * blockDim.x + threadIdx.x) >> 6;
    if (n >= N) return;
    const int base = (m * NB + (n >> 6)) * CAP;
    int s = ((n & 63) == 0) ? base : rows[(size_t)m * N + n - 1];
    int e = rows[(size_t)m * N + n];
    const unsigned short* hg = h + g * 64 + lane;
    float acc = 0.f;
    int i = s;
    for (; i + 3 < e; i += 4) {
        unsigned s0 = cols[i], s1 = cols[i + 1], s2 = cols[i + 2], s3 = cols[i + 3];
        float v0 = bf2f(hg[(size_t)s0 * 192]);
        float v1 = bf2f(hg[(size_t)s1 * 192]);
        float v2 = bf2f(hg[(size_t)s2 * 192]);
        float v3 = bf2f(hg[(size_t)s3 * 192]);
        acc += (v0 + v1) + (v2 + v3);
    }
    for (; i < e; ++i) acc += bf2f(hg[(size_t)cols[i] * 192]);
    f[(size_t)n * 192 + g * 64 + lane] = fmaxf(acc, 0.f);
}

// segment-pool f (already relu'd) by sorted batch_idx.
__global__ void pool_kernel(const float* __restrict__ f, const int* __restrict__ bidx,
                            int N, float* __restrict__ pooled) {
    const int c  = threadIdx.x;          // 0..191
    const int r0 = blockIdx.x * 256;
    const int r1 = min(r0 + 256, N);
    if (r0 >= N) return;
    float acc = 0.f;
    int cur = bidx[r0];
    for (int r = r0; r < r1; ++r) {
        int b = bidx[r];
        if (b != cur) {
            atomicAdd(&pooled[(size_t)cur * 192 + c], acc);
            acc = 0.f;
            cur = b;
        }
        acc += f[(size_t)r * 192 + c];
    }
    atomicAdd(&pooled[(size_t)cur * 192 + c], acc);
}

__global__ void mlp_kernel(const float* __restrict__ pooled,
                           const float* __restrict__ A1, const float* __restrict__ ba1,
                           const float* __restrict__ A2, const float* __restrict__ ba2,
                           float* __restrict__ out) {
    __shared__ float p[192];
    __shared__ float hid[256];
    const int b = blockIdx.x;
    const int t = threadIdx.x;
    if (t < 192) p[t] = pooled[(size_t)b * 192 + t];
    __syncthreads();
    float acc = ba1[t];
    for (int k = 0; k < 192; ++k) acc += p[k] * A1[(size_t)k * 256 + t];
    hid[t] = fmaxf(acc, 0.f);
    __syncthreads();
    if (t < 10) {
        float o = ba2[t];
        for (int k = 0; k < 256; ++k) o += hid[k] * A2[(size_t)k * 10 + t];
        out[(size_t)b * 10 + t] = o;
    }
}

extern "C" void kernel_launch(void* const* d_in, const int* in_sizes, int n_in,
                              void* d_out, int out_size, void* d_ws, size_t ws_size,
                              hipStream_t stream) {
    const float* x      = (const float*)d_in[0];
    const int*   map00  = (const int*)d_in[1];
    const int*   map01  = (const int*)d_in[2];
    const int*   map02  = (const int*)d_in[3];
    const int*   map10  = (const int*)d_in[4];
    const int*   map11  = (const int*)d_in[5];
    const int*   map12  = (const int*)d_in[6];
    const int*   bidx   = (const int*)d_in[7];
    const float* W00 = (const float*)d_in[9];  const float* b00 = (const float*)d_in[10];
    const float* W01 = (const float*)d_in[11]; const float* b01 = (const float*)d_in[12];
    const float* W02 = (const float*)d_in[13]; const float* b02 = (const float*)d_in[14];
    const float* W10 = (const float*)d_in[15]; const float* b10 = (const float*)d_in[16];
    const float* W11 = (const float*)d_in[17]; const float* b11 = (const float*)d_in[18];
    const float* W12 = (const float*)d_in[19]; const float* b12 = (const float*)d_in[20];
    const float* A1  = (const float*)d_in[21]; const float* ba1 = (const float*)d_in[22];
    const float* A2  = (const float*)d_in[23]; const float* ba2 = (const float*)d_in[24];

    const int N  = in_sizes[0] / 128;
    const int E  = in_sizes[1] / 2;
    const int NB = (N + 63) >> 6;              // buckets of 64 nodes

    unsigned short* bufH = (unsigned short*)d_ws;               // [N,192] bf16
    float*    bufF   = (float*)(bufH + (size_t)N * 192);        // [N,192] f32
    float*    pooled = bufF + (size_t)N * 192;                  // [64,192]
    int*      cnt    = (int*)(pooled + 64 * 192);               // 6*NB
    unsigned* part   = (unsigned*)(cnt + 6 * NB);               // 6*NB*CAP
    int*      rows   = (int*)(part + (size_t)6 * NB * CAP);     // 6*N
    unsigned short* wpack = (unsigned short*)(rows + (size_t)6 * N); // 6*12288 bf16

    dim3 gemmGrid((N + 63) / 64, 3);
    dim3 partGrid((E + CHUNK - 1) / CHUNK, 6);
    dim3 sortGrid(NB, 6);
    dim3 aggGrid((N + 3) / 4, 3);

    // build CSR for all 6 maps + pack weights up front
    hipMemsetAsync(cnt, 0, (size_t)6 * NB * sizeof(int), stream);
    prepack_w<<<6, 256, 0, stream>>>(W00, W01, W02, W10, W11, W12, wpack);
    partition_kernel<<<partGrid, PTHREADS, 0, stream>>>(map00, map01, map02,
                                                        map10, map11, map12,
                                                        E, NB, cnt, part);
    bucket_sort<<<sortGrid, 256, 0, stream>>>(NB, N, cnt, part, rows);
    // layer 0
    gemm_mfma<<<gemmGrid, 256, 0, stream>>>(x, N, 128, wpack, b00, b01, b02, 0, bufH);
    csr_agg<<<aggGrid, 256, 0, stream>>>(bufH, rows, part, N, NB, 0, bufF);
    // layer 1
    gemm_mfma<<<gemmGrid, 256, 0, stream>>>(bufF, N, 192, wpack, b10, b11, b12, 3, bufH);
    csr_agg<<<aggGrid, 256, 0, stream>>>(bufH, rows, part, N, NB, 3, bufF);
    // pool + mlp
    hipMemsetAsync(pooled, 0, 64 * 192 * sizeof(float), stream);
    pool_kernel<<<(N + 255) / 256, 192, 0, stream>>>(bufF, bidx, N, pooled);
    mlp_kernel<<<64, 256, 0, stream>>>(pooled, A1, ba1, A2, ba2, (float*)d_out);
}